// Round 11
// baseline (2052.842 us; speedup 1.0000x reference)
//
#include <hip/hip_runtime.h>
#include <math.h>

// Shapes: B=2, N=1024 (H=W=32), C=256, HEADS=8, dh=32, HID=1024, H2=512.
#define TOKS 2048

using bf16x8 = __attribute__((ext_vector_type(8))) short;
using f32x4  = __attribute__((ext_vector_type(4))) float;

__device__ __forceinline__ short f2bf(float f) {
    union { float f; unsigned u; } v; v.f = f;
    unsigned r = v.u + 0x7fff + ((v.u >> 16) & 1);   // RNE bf16 (finite inputs)
    return (short)(r >> 16);
}

__device__ __forceinline__ float gelu_exact(float t) {
    return 0.5f * t * (1.f + erff(t * 0.70710678118654752f));
}

// ---------------- LayerNorm over 256 channels ----------------
__global__ __launch_bounds__(256) void ln256_kernel(const float* __restrict__ x,
    const float* __restrict__ g, const float* __restrict__ bb, float* __restrict__ out) {
    __shared__ float r1[4], r2[4], ms[2];
    int row = blockIdx.x, tid = threadIdx.x;
    float v = x[(size_t)row * 256 + tid];
    float s1 = v, s2 = v * v;
#pragma unroll
    for (int o = 32; o; o >>= 1) { s1 += __shfl_down(s1, o); s2 += __shfl_down(s2, o); }
    if ((tid & 63) == 0) { r1[tid >> 6] = s1; r2[tid >> 6] = s2; }
    __syncthreads();
    if (tid == 0) {
        float a = r1[0] + r1[1] + r1[2] + r1[3];
        float c = r2[0] + r2[1] + r2[2] + r2[3];
        float m = a * (1.f / 256.f);
        float var = c * (1.f / 256.f) - m * m;
        ms[0] = m; ms[1] = rsqrtf(var + 1e-5f);
    }
    __syncthreads();
    out[(size_t)row * 256 + tid] = (v - ms[0]) * ms[1] * g[tid] + bb[tid];
}

// ---------------- LayerNorm(1024) + exact GELU ----------------
__global__ __launch_bounds__(256) void lngelu_kernel(const float* __restrict__ hcat,
    const float* __restrict__ g, const float* __restrict__ bb, float* __restrict__ hg) {
    __shared__ float r1[4], r2[4], ms[2];
    int row = blockIdx.x, tid = threadIdx.x;
    float4 v = reinterpret_cast<const float4*>(hcat + (size_t)row * 1024)[tid];
    float s1 = v.x + v.y + v.z + v.w;
    float s2 = v.x * v.x + v.y * v.y + v.z * v.z + v.w * v.w;
#pragma unroll
    for (int o = 32; o; o >>= 1) { s1 += __shfl_down(s1, o); s2 += __shfl_down(s2, o); }
    if ((tid & 63) == 0) { r1[tid >> 6] = s1; r2[tid >> 6] = s2; }
    __syncthreads();
    if (tid == 0) {
        float a = r1[0] + r1[1] + r1[2] + r1[3];
        float c = r2[0] + r2[1] + r2[2] + r2[3];
        float m = a * (1.f / 1024.f);
        float var = c * (1.f / 1024.f) - m * m;
        ms[0] = m; ms[1] = rsqrtf(var + 1e-5f);
    }
    __syncthreads();
    float4 gv = reinterpret_cast<const float4*>(g)[tid];
    float4 bv = reinterpret_cast<const float4*>(bb)[tid];
    float m = ms[0], inv = ms[1];
    float4 o4;
    o4.x = gelu_exact((v.x - m) * inv * gv.x + bv.x);
    o4.y = gelu_exact((v.y - m) * inv * gv.y + bv.y);
    o4.z = gelu_exact((v.z - m) * inv * gv.z + bv.z);
    o4.w = gelu_exact((v.w - m) * inv * gv.w + bv.w);
    reinterpret_cast<float4*>(hg + (size_t)row * 1024)[tid] = o4;
}

// ---------------- generic fp32 tiled GEMM ----------------
__global__ __launch_bounds__(256) void gemm64_kernel(
    const float* __restrict__ A, const float* __restrict__ W,
    const float* __restrict__ bias, const float* __restrict__ resid,
    float* __restrict__ Cout, int K, int lda, int ldw, int ldc,
    int col_off, int ldres, int mode) {
    __shared__ float As[16][64];
    __shared__ float Ws[16][64];
    int tid = threadIdx.x;
    int n0 = blockIdx.x * 64, m0 = blockIdx.y * 64;
    int ty = tid >> 4, tx = tid & 15;
    int amm = tid >> 2, akk = (tid & 3) * 4;
    int wkk = tid >> 4, wnn = (tid & 15) * 4;
    float acc[4][4] = {};
    for (int k0 = 0; k0 < K; k0 += 16) {
        float4 a4 = *reinterpret_cast<const float4*>(&A[(size_t)(m0 + amm) * lda + k0 + akk]);
        float4 w4 = *reinterpret_cast<const float4*>(&W[(size_t)(k0 + wkk) * ldw + n0 + wnn]);
        As[akk + 0][amm] = a4.x; As[akk + 1][amm] = a4.y;
        As[akk + 2][amm] = a4.z; As[akk + 3][amm] = a4.w;
        *reinterpret_cast<float4*>(&Ws[wkk][wnn]) = w4;
        __syncthreads();
#pragma unroll
        for (int kk = 0; kk < 16; kk++) {
            float4 av = *reinterpret_cast<const float4*>(&As[kk][ty * 4]);
            float4 bv = *reinterpret_cast<const float4*>(&Ws[kk][tx * 4]);
            float a[4] = {av.x, av.y, av.z, av.w};
            float b[4] = {bv.x, bv.y, bv.z, bv.w};
#pragma unroll
            for (int i = 0; i < 4; i++)
#pragma unroll
                for (int j = 0; j < 4; j++) acc[i][j] += a[i] * b[j];
        }
        __syncthreads();
    }
#pragma unroll
    for (int i = 0; i < 4; i++) {
        int r = m0 + ty * 4 + i;
#pragma unroll
        for (int j = 0; j < 4; j++) {
            int c = n0 + tx * 4 + j;
            float v = acc[i][j] + bias[c];
            if (resid) v += resid[(size_t)r * ldres + c];
            if (mode == 0) Cout[(size_t)r * ldc + col_off + c] = v;
            else Cout[(size_t)(r >> 10) * 1048576 + (size_t)c * 1024 + (r & 1023)] = v;
        }
    }
}

// ---------------- attention: one block per (b, head, 8 q-rows) ----------------
#define QT 8
__global__ __launch_bounds__(256) void attn_kernel(const float* __restrict__ qkv,
                                                   float* __restrict__ attn_o) {
    __shared__ float S[QT][1028];
    __shared__ float KV[128][33];
    __shared__ float rowsum[QT];
    int tid = threadIdx.x;
    int qt = blockIdx.x, hd = blockIdx.y, b = blockIdx.z;
    const float* base = qkv + (size_t)b * 1024 * 768;
    int q0 = qt * QT;
    int sqi = tid >> 5, sks = tid & 31;
    float qreg[32];
    const float* qp = base + (size_t)(q0 + sqi) * 768 + hd * 32;
#pragma unroll
    for (int d = 0; d < 32; d++) qreg[d] = qp[d];
    for (int kc = 0; kc < 1024; kc += 128) {
        __syncthreads();
        for (int i = tid; i < 128 * 32; i += 256) {
            int ki = i >> 5, d = i & 31;
            KV[ki][d] = base[(size_t)(kc + ki) * 768 + 256 + hd * 32 + d];
        }
        __syncthreads();
#pragma unroll
        for (int s = 0; s < 4; s++) {
            int ki = sks + 32 * s;
            float acc = 0.f;
#pragma unroll
            for (int d = 0; d < 32; d++) acc += qreg[d] * KV[ki][d];
            S[sqi][kc + ki] = acc * 0.17677669529663687f;
        }
    }
    __syncthreads();
    {
        int row = tid >> 5, l = tid & 31;
        float mx = -1e30f;
        for (int i = l; i < 1024; i += 32) mx = fmaxf(mx, S[row][i]);
#pragma unroll
        for (int o = 16; o; o >>= 1) mx = fmaxf(mx, __shfl_xor(mx, o));
        float sum = 0.f;
        for (int i = l; i < 1024; i += 32) {
            float e = __expf(S[row][i] - mx);
            S[row][i] = e; sum += e;
        }
#pragma unroll
        for (int o = 16; o; o >>= 1) sum += __shfl_xor(sum, o);
        if (l == 0) rowsum[row] = sum;
    }
    float acc = 0.f;
    int d = tid & 31, qi = tid >> 5;
    for (int vc = 0; vc < 1024; vc += 128) {
        __syncthreads();
        for (int i = tid; i < 128 * 32; i += 256) {
            int ki = i >> 5, dd = i & 31;
            KV[ki][dd] = base[(size_t)(vc + ki) * 768 + 512 + hd * 32 + dd];
        }
        __syncthreads();
        for (int m = 0; m < 128; m++) acc += S[qi][vc + m] * KV[m][d];
    }
    attn_o[(size_t)((b << 10) + q0 + qi) * 256 + hd * 32 + d] = acc / rowsum[qi];
}

// ---------------- ibpp grouped 8x8 linears ----------------
__global__ __launch_bounds__(256) void ibpp_kernel(
    const float* __restrict__ h, const float* __restrict__ wi, const float* __restrict__ bi,
    const float* __restrict__ wo, const float* __restrict__ bo, float* __restrict__ cat) {
    __shared__ float Wi[64], Wo[64], Bi[8], Bo[8];
    int tid = threadIdx.x;
    if (tid < 64) { Wi[tid] = wi[tid]; Wo[tid] = wo[tid]; }
    if (tid < 8) { Bi[tid] = bi[tid]; Bo[tid] = bo[tid]; }
    __syncthreads();
    int gi = blockIdx.x * 256 + tid;
    int tok = gi >> 5, grp = gi & 31;
    const float* hp = h + (size_t)tok * 256 + grp * 8;
    float4 a = *reinterpret_cast<const float4*>(hp);
    float4 b4 = *reinterpret_cast<const float4*>(hp + 4);
    float v[8] = {a.x, a.y, a.z, a.w, b4.x, b4.y, b4.z, b4.w};
    float tm[8];
#pragma unroll
    for (int j = 0; j < 8; j++) {
        float s = Bi[j];
#pragma unroll
        for (int i = 0; i < 8; i++) s += v[i] * Wi[i * 8 + j];
        tm[j] = s / (1.f + __expf(-s));
    }
    float* cp = cat + (size_t)tok * 512 + 256 + grp * 8;
#pragma unroll
    for (int j = 0; j < 8; j++) {
        float s = Bo[j];
#pragma unroll
        for (int i = 0; i < 8; i++) s += tm[i] * Wo[i * 8 + j];
        cp[j] = s;
    }
}

// ---------------- offset conv v3: 16 channel-chunks of 32, atomic accumulate ----------------
// grid (4 pixblk, OC, b*16 + cchunk). No bias (folded into mktab).
template <int K, int PAD>
__global__ __launch_bounds__(256) void offconv_kernel(
    const float* __restrict__ plane, int coff,
    const float* __restrict__ W, float* __restrict__ out, int OC) {
    const int K2 = K * K;
    int pix = blockIdx.x * 256 + threadIdx.x;
    int oc = blockIdx.y;
    int zb = blockIdx.z;
    int b = zb >> 4, cc = zb & 15;
    int h = pix >> 5, w = pix & 31;
    int vofs[K2]; float vmsk[K2];
#pragma unroll
    for (int t = 0; t < K2; t++) {
        int yy = h + t / K - PAD, xx = w + t % K - PAD;
        bool v = (yy >= 0 && yy < 32 && xx >= 0 && xx < 32);
        int yc = min(max(yy, 0), 31), xc = min(max(xx, 0), 31);
        vofs[t] = yc * 32 + xc; vmsk[t] = v ? 1.f : 0.f;
    }
    const float* Xb = plane + (size_t)b * 1048576 + (size_t)(coff + cc * 32) * 1024;
    const float* Wo = W + ((size_t)oc * 512 + cc * 32) * K2;
    float acc = 0.f;
    for (int c = 0; c < 32; c++) {
        const float* Xc = Xb + (size_t)c * 1024;
        const float* Wc = Wo + c * K2;
#pragma unroll
        for (int t = 0; t < K2; t++) acc += Wc[t] * (Xc[vofs[t]] * vmsk[t]);
    }
    atomicAdd(&out[((size_t)b * OC + oc) * 1024 + pix], acc);
}

// ---------------- bilinear table build (adds offset bias) ----------------
template <int K, int PAD>
__global__ __launch_bounds__(256) void mktab_kernel(
    const float* __restrict__ off, const float* __restrict__ off_b,
    int4* __restrict__ tabO, float4* __restrict__ tabW) {
    const int K2 = K * K;
    int pix = blockIdx.x * 256 + threadIdx.x;
    int t = blockIdx.y, b = blockIdx.z;
    int h = pix >> 5, w = pix & 31;
    float oy = off[((size_t)(b * 2 * K2) + 2 * t) * 1024 + pix] + off_b[2 * t];
    float ox = off[((size_t)(b * 2 * K2) + 2 * t + 1) * 1024 + pix] + off_b[2 * t + 1];
    float py = (float)(h - PAD + t / K) + oy;
    float px = (float)(w - PAD + t % K) + ox;
    float y0f = floorf(py), x0f = floorf(px);
    float dy = py - y0f, dx = px - x0f;
    int y0 = (int)y0f, x0 = (int)x0f;
    int4 o; float4 wt;
    auto mk = [&](int iy, int ix, float wgt, int& oo, float& ww) {
        bool v = (iy >= 0 && iy <= 31 && ix >= 0 && ix <= 31);
        int iyc = min(max(iy, 0), 31), ixc = min(max(ix, 0), 31);
        oo = iyc * 32 + ixc; ww = v ? wgt : 0.f;
    };
    mk(y0, x0, (1.f - dy) * (1.f - dx), o.x, wt.x);
    mk(y0, x0 + 1, (1.f - dy) * dx, o.y, wt.y);
    mk(y0 + 1, x0, dy * (1.f - dx), o.z, wt.z);
    mk(y0 + 1, x0 + 1, dy * dx, o.w, wt.w);
    tabO[((size_t)b * K2 + t) * 1024 + pix] = o;
    tabW[((size_t)b * K2 + t) * 1024 + pix] = wt;
}

// ---------------- W prep: fp32 OIHW -> bf16 tap-major Wp[oc][t*512+c] ----------------
__global__ __launch_bounds__(256) void wconv_prep_kernel(
    const float* __restrict__ w3, const float* __restrict__ w5,
    short* __restrict__ wp3, short* __restrict__ wp5) {
    __shared__ float wl[12800];
    int oc = blockIdx.x, sel = blockIdx.y, tid = threadIdx.x;
    const int K2 = sel ? 25 : 9;
    const int KK = K2 * 512;
    const float* src = (sel ? w5 : w3) + (size_t)oc * KK;
    short* dst = (sel ? wp5 : wp3) + (size_t)oc * KK;
    for (int i = tid; i < KK; i += 256) wl[i] = src[i];
    __syncthreads();
    for (int i = tid; i < KK; i += 256) {
        int t = i >> 9, c = i & 511;
        dst[i] = f2bf(wl[c * K2 + t]);
    }
}

// ---------------- output init with bias ----------------
__global__ __launch_bounds__(256) void initc_kernel(float* __restrict__ dst,
                                                    const float* __restrict__ bias) {
    int row = blockIdx.x;             // b*512 + oc, grid 1024
    float v = bias[row & 511];
    reinterpret_cast<float4*>(dst + (size_t)row * 1024)[threadIdx.x] = make_float4(v, v, v, v);
}

// pcv[b][ch][pix] init with bias (ch<512: b3, else b5)
__global__ __launch_bounds__(256) void initpcv_kernel(float* __restrict__ pcv,
    const float* __restrict__ b3, const float* __restrict__ b5) {
    int row = blockIdx.x;             // b*1024 + ch, grid 2048
    int ch = row & 1023;
    float v = ch < 512 ? b3[ch] : b5[ch - 512];
    reinterpret_cast<float4*>(pcv + (size_t)row * 1024)[threadIdx.x] = make_float4(v, v, v, v);
}

// transpose pcv[b][ch][pix] -> hcat[b*1024+pix][ch]
__global__ __launch_bounds__(256) void tpose_kernel(const float* __restrict__ pcv,
                                                    float* __restrict__ hcat) {
    __shared__ float T[32][33];
    int px0 = blockIdx.x * 32, ch0 = blockIdx.y * 32, b = blockIdx.z;
    int tx = threadIdx.x & 31, ty = threadIdx.x >> 5;   // 32x8
    const float* src = pcv + ((size_t)b * 1024 + ch0) * 1024 + px0;
#pragma unroll
    for (int i = 0; i < 4; i++) {
        int r = ty + i * 8;
        T[r][tx] = src[(size_t)r * 1024 + tx];
    }
    __syncthreads();
    float* dst = hcat + ((size_t)(b << 10) + px0) * 1024 + ch0;
#pragma unroll
    for (int i = 0; i < 4; i++) {
        int r = ty + i * 8;
        dst[(size_t)r * 1024 + tx] = T[tx][r];
    }
}

// ---------------- deform sampling: LDS-staged channel, LDS gather -> bf16 samp ----------------
template <int K2>
__global__ __launch_bounds__(256) void dsamp_kernel(
    const float* __restrict__ plane, int coff,
    const int4* __restrict__ tabO, const float4* __restrict__ tabW,
    short* __restrict__ samp) {
    __shared__ float Xl[1024];
    int c = blockIdx.x, b = blockIdx.y, tid = threadIdx.x;
    const float* Xc = plane + (size_t)b * 1048576 + (size_t)(coff + c) * 1024;
    reinterpret_cast<float4*>(Xl)[tid] = reinterpret_cast<const float4*>(Xc)[tid];
    __syncthreads();
    const int4* tO = tabO + (size_t)b * K2 * 1024;
    const float4* tW = tabW + (size_t)b * K2 * 1024;
    short* sb = samp + (size_t)b * K2 * 512 * 1024;
    int p4 = tid * 4;
    for (int t = 0; t < K2; t++) {
        short4 r4;
        short* rp = (short*)&r4;
#pragma unroll
        for (int q = 0; q < 4; q++) {
            int4 o = tO[t * 1024 + p4 + q];
            float4 wv = tW[t * 1024 + p4 + q];
            float v = wv.x * Xl[o.x] + wv.y * Xl[o.y] + wv.z * Xl[o.z] + wv.w * Xl[o.w];
            rp[q] = f2bf(v);
        }
        *reinterpret_cast<short4*>(&sb[(size_t)(t * 512 + c) * 1024 + p4]) = r4;
    }
}

// ======== conv GEMMs (bf16 MFMA, K-step 64, tap-chunk K-split, coalesced atomics) ========
// Tile 64 oc x 64 pix, 4 waves. Fragment layouts verified rounds 4-10.
// MODE 0 (deform): B from samp bf16. Epilogue -> out[b][oc][pix] (coalesced atomics).
// MODE 1 (plain): B from dcv fp32 inline shift+mask. Epilogue -> pcv[b][ch_off+oc][pix] (coalesced).
template <int K2, int TPC, int MODE>
__global__ __launch_bounds__(256) void conv_gemm_kernel(
    const short* __restrict__ samp, const float* __restrict__ dcv,
    const short* __restrict__ Wp, float* __restrict__ out, int ch_off) {
    const int K = (K2 == 9) ? 3 : 5, PAD = (K2 == 9) ? 1 : 2;
    __shared__ short S16[64][66];
    const int KK = 512 * K2;
    const int NCHUNK = K2 / TPC;
    int tid = threadIdx.x;
    int lane = tid & 63, wave = tid >> 6;
    int p0 = blockIdx.x * 64, oc0 = blockIdx.y * 64;
    int bz = blockIdx.z;
    int b = bz / NCHUNK, chunk = bz % NCHUNK;
    int jrow = tid >> 2, pq = (tid & 3) * 16;          // staging: 64 k-rows x 64 pix
    int frag_pix = wave * 16 + (lane & 15);
    int frag_k0 = (lane >> 4) * 8;
    int arow = oc0 + (lane & 15);
    const short* sb = samp + (size_t)b * KK * 1024;
    const float* Xb = dcv + (MODE == 1 ? (size_t)b * 524288 : 0);
    f32x4 acc[4];
#pragma unroll
    for (int m = 0; m < 4; m++) acc[m] = (f32x4){0.f, 0.f, 0.f, 0.f};
    int t0 = chunk * TPC;
    for (int tt = t0; tt < t0 + TPC; ++tt) {
        int dy = tt / K - PAD, dx = tt % K - PAD;
        for (int c0 = 0; c0 < 512; c0 += 64) {
            unsigned* sdst = reinterpret_cast<unsigned*>(&S16[jrow][pq]);   // 8 dwords
            if constexpr (MODE == 0) {
                const unsigned* g = reinterpret_cast<const unsigned*>(
                    &sb[(size_t)(tt * 512 + c0 + jrow) * 1024 + p0 + pq]);
#pragma unroll
                for (int k = 0; k < 8; k++) sdst[k] = g[k];
            } else {
                const float* Xc = Xb + (size_t)(c0 + jrow) * 1024;
#pragma unroll
                for (int k = 0; k < 8; k++) {
                    unsigned u = 0;
#pragma unroll
                    for (int e = 0; e < 2; e++) {
                        int p = p0 + pq + k * 2 + e;
                        int yy = (p >> 5) + dy, xx = (p & 31) + dx;
                        bool valid = ((unsigned)yy < 32u) && ((unsigned)xx < 32u);
                        float v = valid ? Xc[(yy << 5) + xx] : 0.f;
                        u |= ((unsigned)(unsigned short)f2bf(v)) << (16 * e);
                    }
                    sdst[k] = u;
                }
            }
            __syncthreads();
#pragma unroll
            for (int ks = 0; ks < 64; ks += 32) {
                bf16x8 bfrag;
#pragma unroll
                for (int r = 0; r < 8; r++) bfrag[r] = S16[ks + frag_k0 + r][frag_pix];
                int jcol = tt * 512 + c0 + ks + frag_k0;
#pragma unroll
                for (int m = 0; m < 4; m++) {
                    bf16x8 afrag = *reinterpret_cast<const bf16x8*>(
                        &Wp[(size_t)(arow + m * 16) * KK + jcol]);
                    acc[m] = __builtin_amdgcn_mfma_f32_16x16x32_bf16(afrag, bfrag, acc[m], 0, 0, 0);
                }
            }
            __syncthreads();
        }
    }
    int orow = (lane >> 4) * 4;
#pragma unroll
    for (int m = 0; m < 4; m++)
#pragma unroll
        for (int r = 0; r < 4; r++) {
            int oc = oc0 + m * 16 + orow + r;
            if constexpr (MODE == 0)
                atomicAdd(&out[((size_t)b * 512 + oc) * 1024 + p0 + frag_pix], acc[m][r]);
            else
                atomicAdd(&out[((size_t)b * 1024 + ch_off + oc) * 1024 + p0 + frag_pix], acc[m][r]);
        }
}

extern "C" void kernel_launch(void* const* d_in, const int* in_sizes, int n_in,
                              void* d_out, int out_size, void* d_ws, size_t ws_size,
                              hipStream_t stream) {
    const float* x        = (const float*)d_in[0];
    const float* ln1_g    = (const float*)d_in[1];
    const float* ln1_b    = (const float*)d_in[2];
    const float* qkv_w    = (const float*)d_in[3];
    const float* qkv_b    = (const float*)d_in[4];
    const float* merge_w  = (const float*)d_in[5];
    const float* merge_b  = (const float*)d_in[6];
    const float* ibpp_in_w  = (const float*)d_in[7];
    const float* ibpp_in_b  = (const float*)d_in[8];
    const float* ibpp_out_w = (const float*)d_in[9];
    const float* ibpp_out_b = (const float*)d_in[10];
    const float* proj_w   = (const float*)d_in[11];
    const float* proj_b   = (const float*)d_in[12];
    const float* ln2_g    = (const float*)d_in[13];
    const float* ln2_b    = (const float*)d_in[14];
    const float* fc1_w    = (const float*)d_in[15];
    const float* fc1_b    = (const float*)d_in[16];
    const float* dc3_off_w = (const float*)d_in[17];
    const float* dc3_off_b = (const float*)d_in[18];
    const float* dc3_w    = (const float*)d_in[19];
    const float* dc3_b    = (const float*)d_in[20];
    const float* dc5_off_w = (const float*)d_in[21];
    const float* dc5_off_b = (const float*)d_in[22];
    const float* dc5_w    = (const float*)d_in[23];
    const float* dc5_b    = (const float*)d_in[24];
    const float* ffn_g    = (const float*)d_in[25];
    const float* ffn_b    = (const float*)d_in[26];
    const float* fc2_w    = (const float*)d_in[27];
    const float* fc2_b    = (const float*)d_in[28];
    float* outp = (float*)d_out;

    float* ws = (float*)d_ws;
    float* h_buf   = ws;                       // 2048x256
    float* qkv_buf = h_buf + 524288;           // 2048x768
    float* attn_o  = qkv_buf + 1572864;        // 2048x256
    float* cat     = attn_o + 524288;          // 2048x512
    float* xres    = cat + 1048576;            // 2048x256
    float* h2a     = xres + 524288;            // 2048x256
    float* plane   = h2a + 524288;             // 2 x 1024ch x 1024pix
    float* dcv3    = plane + 2097152;          // 2 x 512 x 1024
    float* dcv5    = dcv3 + 1048576;           // 2 x 512 x 1024
    float* hcat    = dcv5 + 1048576;           // 2048 x 1024
    float* hg      = hcat + 2097152;           // 2048 x 1024
    float* off3    = hg + 2097152;             // 2 x 18 x 1024
    float* off5    = off3 + 36864;             // 2 x 50 x 1024
    float* tab3W_f = off5 + 102400;            // 2*9*1024 float4
    float* tab5W_f = tab3W_f + 73728;          // 2*25*1024 float4
    float* tab3O_f = tab5W_f + 204800;         // 2*9*1024 int4
    float* tab5O_f = tab3O_f + 73728;          // 2*25*1024 int4
    short* wp3     = (short*)(tab5O_f + 204800);  // 512x4608 bf16
    short* wp5     = wp3 + 2359296;               // 512x12800 bf16
    short* samp    = wp5 + 6553600;               // 2x25x512x1024 bf16 (shared 3/5)
    float* pcv     = (float*)(samp + 26214400);   // 2 x 1024 x 1024 (plain-conv partials)

    // ---- prep: W -> bf16 tap-major ----
    wconv_prep_kernel<<<dim3(512, 2), 256, 0, stream>>>(dc3_w, dc5_w, wp3, wp5);

    // ---- attention branch ----
    ln256_kernel<<<2048, 256, 0, stream>>>(x, ln1_g, ln1_b, h_buf);
    gemm64_kernel<<<dim3(12, 32), 256, 0, stream>>>(h_buf, qkv_w, qkv_b, nullptr, qkv_buf,
                                                    256, 256, 768, 768, 0, 0, 0);
    attn_kernel<<<dim3(128, 8, 2), 256, 0, stream>>>(qkv_buf, attn_o);
    gemm64_kernel<<<dim3(4, 32), 256, 0, stream>>>(attn_o, merge_w, merge_b, nullptr, cat,
                                                   256, 256, 256, 512, 0, 0, 0);
    ibpp_kernel<<<256, 256, 0, stream>>>(h_buf, ibpp_in_w, ibpp_in_b, ibpp_out_w, ibpp_out_b, cat);
    gemm64_kernel<<<dim3(4, 32), 256, 0, stream>>>(cat, proj_w, proj_b, x, xres,
                                                   512, 512, 256, 256, 0, 256, 0);
    // ---- EHFF branch ----
    ln256_kernel<<<2048, 256, 0, stream>>>(xres, ln2_g, ln2_b, h2a);
    gemm64_kernel<<<dim3(16, 32), 256, 0, stream>>>(h2a, fc1_w, fc1_b, nullptr, plane,
                                                    256, 256, 1024, 0, 0, 0, 1);
    // offset convs: zero accumulators, channel-chunked atomics (bias folded into mktab)
    hipMemsetAsync(off3, 0, (36864 + 102400) * sizeof(float), stream);
    offconv_kernel<3, 1><<<dim3(4, 18, 32), 256, 0, stream>>>(plane, 0, dc3_off_w, off3, 18);
    offconv_kernel<5, 2><<<dim3(4, 50, 32), 256, 0, stream>>>(plane, 512, dc5_off_w, off5, 50);
    mktab_kernel<3, 1><<<dim3(4, 9, 2), 256, 0, stream>>>(off3, dc3_off_b, (int4*)tab3O_f, (float4*)tab3W_f);
    mktab_kernel<5, 2><<<dim3(4, 25, 2), 256, 0, stream>>>(off5, dc5_off_b, (int4*)tab5O_f, (float4*)tab5W_f);
    initc_kernel<<<1024, 256, 0, stream>>>(dcv3, dc3_b);
    initc_kernel<<<1024, 256, 0, stream>>>(dcv5, dc5_b);
    initpcv_kernel<<<2048, 256, 0, stream>>>(pcv, dc3_b, dc5_b);
    // deform conv 3x3: sample -> GEMM
    dsamp_kernel<9><<<dim3(512, 2), 256, 0, stream>>>(plane, 0,
        (const int4*)tab3O_f, (const float4*)tab3W_f, samp);
    conv_gemm_kernel<9, 3, 0><<<dim3(16, 8, 6), 256, 0, stream>>>(samp, nullptr, wp3, dcv3, 0);
    // deform conv 5x5: sample -> GEMM (samp buffer reused)
    dsamp_kernel<25><<<dim3(512, 2), 256, 0, stream>>>(plane, 512,
        (const int4*)tab5O_f, (const float4*)tab5W_f, samp);
    conv_gemm_kernel<25, 5, 0><<<dim3(16, 8, 10), 256, 0, stream>>>(samp, nullptr, wp5, dcv5, 0);
    // plain convs (inline shift) -> pcv (coalesced), then transpose to hcat
    conv_gemm_kernel<9, 3, 1><<<dim3(16, 8, 6), 256, 0, stream>>>(nullptr, dcv3, wp3, pcv, 0);
    conv_gemm_kernel<25, 5, 1><<<dim3(16, 8, 10), 256, 0, stream>>>(nullptr, dcv5, wp5, pcv, 512);
    tpose_kernel<<<dim3(32, 32, 2), 256, 0, stream>>>(pcv, hcat);
    lngelu_kernel<<<2048, 256, 0, stream>>>(hcat, ffn_g, ffn_b, hg);
    gemm64_kernel<<<dim3(4, 32), 256, 0, stream>>>(hg, fc2_w, fc2_b, xres, outp,
                                                   1024, 1024, 256, 256, 0, 256, 0);
}

// Round 12
// 1497.949 us; speedup vs baseline: 1.3704x; 1.3704x over previous
//
#include <hip/hip_runtime.h>
#include <math.h>

// Shapes: B=2, N=1024 (H=W=32), C=256, HEADS=8, dh=32, HID=1024, H2=512.
#define TOKS 2048

using bf16x8 = __attribute__((ext_vector_type(8))) short;
using f32x4  = __attribute__((ext_vector_type(4))) float;

__device__ __forceinline__ short f2bf(float f) {
    union { float f; unsigned u; } v; v.f = f;
    unsigned r = v.u + 0x7fff + ((v.u >> 16) & 1);   // RNE bf16 (finite inputs)
    return (short)(r >> 16);
}

__device__ __forceinline__ float gelu_exact(float t) {
    return 0.5f * t * (1.f + erff(t * 0.70710678118654752f));
}

// ---------------- LayerNorm over 256 channels ----------------
__global__ __launch_bounds__(256) void ln256_kernel(const float* __restrict__ x,
    const float* __restrict__ g, const float* __restrict__ bb, float* __restrict__ out) {
    __shared__ float r1[4], r2[4], ms[2];
    int row = blockIdx.x, tid = threadIdx.x;
    float v = x[(size_t)row * 256 + tid];
    float s1 = v, s2 = v * v;
#pragma unroll
    for (int o = 32; o; o >>= 1) { s1 += __shfl_down(s1, o); s2 += __shfl_down(s2, o); }
    if ((tid & 63) == 0) { r1[tid >> 6] = s1; r2[tid >> 6] = s2; }
    __syncthreads();
    if (tid == 0) {
        float a = r1[0] + r1[1] + r1[2] + r1[3];
        float c = r2[0] + r2[1] + r2[2] + r2[3];
        float m = a * (1.f / 256.f);
        float var = c * (1.f / 256.f) - m * m;
        ms[0] = m; ms[1] = rsqrtf(var + 1e-5f);
    }
    __syncthreads();
    out[(size_t)row * 256 + tid] = (v - ms[0]) * ms[1] * g[tid] + bb[tid];
}

// ---------------- LayerNorm(1024) + exact GELU ----------------
__global__ __launch_bounds__(256) void lngelu_kernel(const float* __restrict__ hcat,
    const float* __restrict__ g, const float* __restrict__ bb, float* __restrict__ hg) {
    __shared__ float r1[4], r2[4], ms[2];
    int row = blockIdx.x, tid = threadIdx.x;
    float4 v = reinterpret_cast<const float4*>(hcat + (size_t)row * 1024)[tid];
    float s1 = v.x + v.y + v.z + v.w;
    float s2 = v.x * v.x + v.y * v.y + v.z * v.z + v.w * v.w;
#pragma unroll
    for (int o = 32; o; o >>= 1) { s1 += __shfl_down(s1, o); s2 += __shfl_down(s2, o); }
    if ((tid & 63) == 0) { r1[tid >> 6] = s1; r2[tid >> 6] = s2; }
    __syncthreads();
    if (tid == 0) {
        float a = r1[0] + r1[1] + r1[2] + r1[3];
        float c = r2[0] + r2[1] + r2[2] + r2[3];
        float m = a * (1.f / 1024.f);
        float var = c * (1.f / 1024.f) - m * m;
        ms[0] = m; ms[1] = rsqrtf(var + 1e-5f);
    }
    __syncthreads();
    float4 gv = reinterpret_cast<const float4*>(g)[tid];
    float4 bv = reinterpret_cast<const float4*>(bb)[tid];
    float m = ms[0], inv = ms[1];
    float4 o4;
    o4.x = gelu_exact((v.x - m) * inv * gv.x + bv.x);
    o4.y = gelu_exact((v.y - m) * inv * gv.y + bv.y);
    o4.z = gelu_exact((v.z - m) * inv * gv.z + bv.z);
    o4.w = gelu_exact((v.w - m) * inv * gv.w + bv.w);
    reinterpret_cast<float4*>(hg + (size_t)row * 1024)[tid] = o4;
}

// ---------------- generic fp32 tiled GEMM ----------------
__global__ __launch_bounds__(256) void gemm64_kernel(
    const float* __restrict__ A, const float* __restrict__ W,
    const float* __restrict__ bias, const float* __restrict__ resid,
    float* __restrict__ Cout, int K, int lda, int ldw, int ldc,
    int col_off, int ldres, int mode) {
    __shared__ float As[16][64];
    __shared__ float Ws[16][64];
    int tid = threadIdx.x;
    int n0 = blockIdx.x * 64, m0 = blockIdx.y * 64;
    int ty = tid >> 4, tx = tid & 15;
    int amm = tid >> 2, akk = (tid & 3) * 4;
    int wkk = tid >> 4, wnn = (tid & 15) * 4;
    float acc[4][4] = {};
    for (int k0 = 0; k0 < K; k0 += 16) {
        float4 a4 = *reinterpret_cast<const float4*>(&A[(size_t)(m0 + amm) * lda + k0 + akk]);
        float4 w4 = *reinterpret_cast<const float4*>(&W[(size_t)(k0 + wkk) * ldw + n0 + wnn]);
        As[akk + 0][amm] = a4.x; As[akk + 1][amm] = a4.y;
        As[akk + 2][amm] = a4.z; As[akk + 3][amm] = a4.w;
        *reinterpret_cast<float4*>(&Ws[wkk][wnn]) = w4;
        __syncthreads();
#pragma unroll
        for (int kk = 0; kk < 16; kk++) {
            float4 av = *reinterpret_cast<const float4*>(&As[kk][ty * 4]);
            float4 bv = *reinterpret_cast<const float4*>(&Ws[kk][tx * 4]);
            float a[4] = {av.x, av.y, av.z, av.w};
            float b[4] = {bv.x, bv.y, bv.z, bv.w};
#pragma unroll
            for (int i = 0; i < 4; i++)
#pragma unroll
                for (int j = 0; j < 4; j++) acc[i][j] += a[i] * b[j];
        }
        __syncthreads();
    }
#pragma unroll
    for (int i = 0; i < 4; i++) {
        int r = m0 + ty * 4 + i;
#pragma unroll
        for (int j = 0; j < 4; j++) {
            int c = n0 + tx * 4 + j;
            float v = acc[i][j] + bias[c];
            if (resid) v += resid[(size_t)r * ldres + c];
            if (mode == 0) Cout[(size_t)r * ldc + col_off + c] = v;
            else Cout[(size_t)(r >> 10) * 1048576 + (size_t)c * 1024 + (r & 1023)] = v;
        }
    }
}

// ---------------- attention: one block per (b, head, 8 q-rows) ----------------
#define QT 8
__global__ __launch_bounds__(256) void attn_kernel(const float* __restrict__ qkv,
                                                   float* __restrict__ attn_o) {
    __shared__ float S[QT][1028];
    __shared__ float KV[128][33];
    __shared__ float rowsum[QT];
    int tid = threadIdx.x;
    int qt = blockIdx.x, hd = blockIdx.y, b = blockIdx.z;
    const float* base = qkv + (size_t)b * 1024 * 768;
    int q0 = qt * QT;
    int sqi = tid >> 5, sks = tid & 31;
    float qreg[32];
    const float* qp = base + (size_t)(q0 + sqi) * 768 + hd * 32;
#pragma unroll
    for (int d = 0; d < 32; d++) qreg[d] = qp[d];
    for (int kc = 0; kc < 1024; kc += 128) {
        __syncthreads();
        for (int i = tid; i < 128 * 32; i += 256) {
            int ki = i >> 5, d = i & 31;
            KV[ki][d] = base[(size_t)(kc + ki) * 768 + 256 + hd * 32 + d];
        }
        __syncthreads();
#pragma unroll
        for (int s = 0; s < 4; s++) {
            int ki = sks + 32 * s;
            float acc = 0.f;
#pragma unroll
            for (int d = 0; d < 32; d++) acc += qreg[d] * KV[ki][d];
            S[sqi][kc + ki] = acc * 0.17677669529663687f;
        }
    }
    __syncthreads();
    {
        int row = tid >> 5, l = tid & 31;
        float mx = -1e30f;
        for (int i = l; i < 1024; i += 32) mx = fmaxf(mx, S[row][i]);
#pragma unroll
        for (int o = 16; o; o >>= 1) mx = fmaxf(mx, __shfl_xor(mx, o));
        float sum = 0.f;
        for (int i = l; i < 1024; i += 32) {
            float e = __expf(S[row][i] - mx);
            S[row][i] = e; sum += e;
        }
#pragma unroll
        for (int o = 16; o; o >>= 1) sum += __shfl_xor(sum, o);
        if (l == 0) rowsum[row] = sum;
    }
    float acc = 0.f;
    int d = tid & 31, qi = tid >> 5;
    for (int vc = 0; vc < 1024; vc += 128) {
        __syncthreads();
        for (int i = tid; i < 128 * 32; i += 256) {
            int ki = i >> 5, dd = i & 31;
            KV[ki][dd] = base[(size_t)(vc + ki) * 768 + 512 + hd * 32 + dd];
        }
        __syncthreads();
        for (int m = 0; m < 128; m++) acc += S[qi][vc + m] * KV[m][d];
    }
    attn_o[(size_t)((b << 10) + q0 + qi) * 256 + hd * 32 + d] = acc / rowsum[qi];
}

// ---------------- ibpp grouped 8x8 linears ----------------
__global__ __launch_bounds__(256) void ibpp_kernel(
    const float* __restrict__ h, const float* __restrict__ wi, const float* __restrict__ bi,
    const float* __restrict__ wo, const float* __restrict__ bo, float* __restrict__ cat) {
    __shared__ float Wi[64], Wo[64], Bi[8], Bo[8];
    int tid = threadIdx.x;
    if (tid < 64) { Wi[tid] = wi[tid]; Wo[tid] = wo[tid]; }
    if (tid < 8) { Bi[tid] = bi[tid]; Bo[tid] = bo[tid]; }
    __syncthreads();
    int gi = blockIdx.x * 256 + tid;
    int tok = gi >> 5, grp = gi & 31;
    const float* hp = h + (size_t)tok * 256 + grp * 8;
    float4 a = *reinterpret_cast<const float4*>(hp);
    float4 b4 = *reinterpret_cast<const float4*>(hp + 4);
    float v[8] = {a.x, a.y, a.z, a.w, b4.x, b4.y, b4.z, b4.w};
    float tm[8];
#pragma unroll
    for (int j = 0; j < 8; j++) {
        float s = Bi[j];
#pragma unroll
        for (int i = 0; i < 8; i++) s += v[i] * Wi[i * 8 + j];
        tm[j] = s / (1.f + __expf(-s));
    }
    float* cp = cat + (size_t)tok * 512 + 256 + grp * 8;
#pragma unroll
    for (int j = 0; j < 8; j++) {
        float s = Bo[j];
#pragma unroll
        for (int i = 0; i < 8; i++) s += tm[i] * Wo[i * 8 + j];
        cp[j] = s;
    }
}

// ---------------- offset conv: 16 channel-chunks of 32, atomic accumulate ----------------
template <int K, int PAD>
__global__ __launch_bounds__(256) void offconv_kernel(
    const float* __restrict__ plane, int coff,
    const float* __restrict__ W, float* __restrict__ out, int OC) {
    const int K2 = K * K;
    int pix = blockIdx.x * 256 + threadIdx.x;
    int oc = blockIdx.y;
    int zb = blockIdx.z;
    int b = zb >> 4, cc = zb & 15;
    int h = pix >> 5, w = pix & 31;
    int vofs[K2]; float vmsk[K2];
#pragma unroll
    for (int t = 0; t < K2; t++) {
        int yy = h + t / K - PAD, xx = w + t % K - PAD;
        bool v = (yy >= 0 && yy < 32 && xx >= 0 && xx < 32);
        int yc = min(max(yy, 0), 31), xc = min(max(xx, 0), 31);
        vofs[t] = yc * 32 + xc; vmsk[t] = v ? 1.f : 0.f;
    }
    const float* Xb = plane + (size_t)b * 1048576 + (size_t)(coff + cc * 32) * 1024;
    const float* Wo = W + ((size_t)oc * 512 + cc * 32) * K2;
    float acc = 0.f;
    for (int c = 0; c < 32; c++) {
        const float* Xc = Xb + (size_t)c * 1024;
        const float* Wc = Wo + c * K2;
#pragma unroll
        for (int t = 0; t < K2; t++) acc += Wc[t] * (Xc[vofs[t]] * vmsk[t]);
    }
    atomicAdd(&out[((size_t)b * OC + oc) * 1024 + pix], acc);
}

// ---------------- bilinear table build (adds offset bias) ----------------
template <int K, int PAD>
__global__ __launch_bounds__(256) void mktab_kernel(
    const float* __restrict__ off, const float* __restrict__ off_b,
    int4* __restrict__ tabO, float4* __restrict__ tabW) {
    const int K2 = K * K;
    int pix = blockIdx.x * 256 + threadIdx.x;
    int t = blockIdx.y, b = blockIdx.z;
    int h = pix >> 5, w = pix & 31;
    float oy = off[((size_t)(b * 2 * K2) + 2 * t) * 1024 + pix] + off_b[2 * t];
    float ox = off[((size_t)(b * 2 * K2) + 2 * t + 1) * 1024 + pix] + off_b[2 * t + 1];
    float py = (float)(h - PAD + t / K) + oy;
    float px = (float)(w - PAD + t % K) + ox;
    float y0f = floorf(py), x0f = floorf(px);
    float dy = py - y0f, dx = px - x0f;
    int y0 = (int)y0f, x0 = (int)x0f;
    int4 o; float4 wt;
    auto mk = [&](int iy, int ix, float wgt, int& oo, float& ww) {
        bool v = (iy >= 0 && iy <= 31 && ix >= 0 && ix <= 31);
        int iyc = min(max(iy, 0), 31), ixc = min(max(ix, 0), 31);
        oo = iyc * 32 + ixc; ww = v ? wgt : 0.f;
    };
    mk(y0, x0, (1.f - dy) * (1.f - dx), o.x, wt.x);
    mk(y0, x0 + 1, (1.f - dy) * dx, o.y, wt.y);
    mk(y0 + 1, x0, dy * (1.f - dx), o.z, wt.z);
    mk(y0 + 1, x0 + 1, dy * dx, o.w, wt.w);
    tabO[((size_t)b * K2 + t) * 1024 + pix] = o;
    tabW[((size_t)b * K2 + t) * 1024 + pix] = wt;
}

// ---------------- W prep: fp32 OIHW -> bf16 tap-major Wp[oc][t*512+c] ----------------
__global__ __launch_bounds__(256) void wconv_prep_kernel(
    const float* __restrict__ w3, const float* __restrict__ w5,
    short* __restrict__ wp3, short* __restrict__ wp5) {
    __shared__ float wl[12800];
    int oc = blockIdx.x, sel = blockIdx.y, tid = threadIdx.x;
    const int K2 = sel ? 25 : 9;
    const int KK = K2 * 512;
    const float* src = (sel ? w5 : w3) + (size_t)oc * KK;
    short* dst = (sel ? wp5 : wp3) + (size_t)oc * KK;
    for (int i = tid; i < KK; i += 256) wl[i] = src[i];
    __syncthreads();
    for (int i = tid; i < KK; i += 256) {
        int t = i >> 9, c = i & 511;
        dst[i] = f2bf(wl[c * K2 + t]);
    }
}

// ---------------- output init with bias ----------------
__global__ __launch_bounds__(256) void initc_kernel(float* __restrict__ dst,
                                                    const float* __restrict__ bias) {
    int row = blockIdx.x;             // b*512 + oc, grid 1024
    float v = bias[row & 511];
    reinterpret_cast<float4*>(dst + (size_t)row * 1024)[threadIdx.x] = make_float4(v, v, v, v);
}

__global__ __launch_bounds__(256) void initpcv_kernel(float* __restrict__ pcv,
    const float* __restrict__ b3, const float* __restrict__ b5) {
    int row = blockIdx.x;             // b*1024 + ch, grid 2048
    int ch = row & 1023;
    float v = ch < 512 ? b3[ch] : b5[ch - 512];
    reinterpret_cast<float4*>(pcv + (size_t)row * 1024)[threadIdx.x] = make_float4(v, v, v, v);
}

// transpose pcv[b][ch][pix] -> hcat[b*1024+pix][ch]
__global__ __launch_bounds__(256) void tpose_kernel(const float* __restrict__ pcv,
                                                    float* __restrict__ hcat) {
    __shared__ float T[32][33];
    int px0 = blockIdx.x * 32, ch0 = blockIdx.y * 32, b = blockIdx.z;
    int tx = threadIdx.x & 31, ty = threadIdx.x >> 5;   // 32x8
    const float* src = pcv + ((size_t)b * 1024 + ch0) * 1024 + px0;
#pragma unroll
    for (int i = 0; i < 4; i++) {
        int r = ty + i * 8;
        T[r][tx] = src[(size_t)r * 1024 + tx];
    }
    __syncthreads();
    float* dst = hcat + ((size_t)(b << 10) + px0) * 1024 + ch0;
#pragma unroll
    for (int i = 0; i < 4; i++) {
        int r = ty + i * 8;
        dst[(size_t)r * 1024 + tx] = T[tx][r];
    }
}

// ---------------- deform sampling: LDS-staged channel, LDS gather -> bf16 samp ----------------
template <int K2>
__global__ __launch_bounds__(256) void dsamp_kernel(
    const float* __restrict__ plane, int coff,
    const int4* __restrict__ tabO, const float4* __restrict__ tabW,
    short* __restrict__ samp) {
    __shared__ float Xl[1024];
    int c = blockIdx.x, b = blockIdx.y, tid = threadIdx.x;
    const float* Xc = plane + (size_t)b * 1048576 + (size_t)(coff + c) * 1024;
    reinterpret_cast<float4*>(Xl)[tid] = reinterpret_cast<const float4*>(Xc)[tid];
    __syncthreads();
    const int4* tO = tabO + (size_t)b * K2 * 1024;
    const float4* tW = tabW + (size_t)b * K2 * 1024;
    short* sb = samp + (size_t)b * K2 * 512 * 1024;
    int p4 = tid * 4;
    for (int t = 0; t < K2; t++) {
        short4 r4;
        short* rp = (short*)&r4;
#pragma unroll
        for (int q = 0; q < 4; q++) {
            int4 o = tO[t * 1024 + p4 + q];
            float4 wv = tW[t * 1024 + p4 + q];
            float v = wv.x * Xl[o.x] + wv.y * Xl[o.y] + wv.z * Xl[o.z] + wv.w * Xl[o.w];
            rp[q] = f2bf(v);
        }
        *reinterpret_cast<short4*>(&sb[(size_t)(t * 512 + c) * 1024 + p4]) = r4;
    }
}

// ---------------- plain-conv sampling: constant shifts from dcv -> bf16 samp ----------------
template <int K2>
__global__ __launch_bounds__(256) void psamp_kernel(
    const float* __restrict__ dcv, short* __restrict__ samp) {
    const int K = (K2 == 9) ? 3 : 5, PAD = (K2 == 9) ? 1 : 2;
    __shared__ float Xl[1024];
    int c = blockIdx.x, b = blockIdx.y, tid = threadIdx.x;
    const float* Xc = dcv + ((size_t)b * 512 + c) * 1024;
    reinterpret_cast<float4*>(Xl)[tid] = reinterpret_cast<const float4*>(Xc)[tid];
    __syncthreads();
    short* sb = samp + (size_t)b * K2 * 512 * 1024;
    int p4 = tid * 4;
    int h = p4 >> 5, w0 = p4 & 31;     // 4 consecutive pixels, same image row
    for (int t = 0; t < K2; t++) {
        int dy = t / K - PAD, dx = t % K - PAD;
        int yy = h + dy;
        bool vy = ((unsigned)yy < 32u);
        int yb = (vy ? yy : 0) << 5;
        short4 r4;
        short* rp = (short*)&r4;
#pragma unroll
        for (int q = 0; q < 4; q++) {
            int xx = w0 + q + dx;
            bool v = vy && ((unsigned)xx < 32u);
            rp[q] = f2bf(v ? Xl[yb + xx] : 0.f);
        }
        *reinterpret_cast<short4*>(&sb[(size_t)(t * 512 + c) * 1024 + p4]) = r4;
    }
}

// ======== unified conv GEMM: bf16 MFMA, register-prefetch pipeline ========
// Tile 64 oc x 64 pix, 4 waves; K-chunk = TPC taps; atomics into bias-init'd out.
// A-frag (Wp): row = lane&15, k = (lane>>4)*8+i.  B-frag: col = lane&15, same k.
// D: col = lane&15 (pixel), row = (lane>>4)*4+r (oc). [verified rounds 4-11]
template <int K2, int TPC>
__global__ __launch_bounds__(256, 4) void conv_gemm_kernel(
    const short* __restrict__ samp, const short* __restrict__ Wp,
    float* __restrict__ out, int OCS, int ch_off) {
    __shared__ short S16[64][66];            // 132-B rows: dword offset 33/row -> bank spread
    const int KK = 512 * K2;
    const int NCHUNK = K2 / TPC;
    const int NIT = TPC * 8;                 // c0 steps of 64 over the chunk
    int tid = threadIdx.x;
    int lane = tid & 63, wave = tid >> 6;
    int p0 = blockIdx.x * 64, oc0 = blockIdx.y * 64;
    int bz = blockIdx.z;
    int b = bz / NCHUNK, chunk = bz % NCHUNK;
    int jrow = tid >> 2, pq = (tid & 3) * 16;   // staging: 64 rows x 64 pix, 32 B/thread
    int frag_pix = wave * 16 + (lane & 15);
    int frag_k0 = (lane >> 4) * 8;
    int arow = oc0 + (lane & 15);
    const short* sb = samp + (size_t)b * KK * 1024;
    int t0 = chunk * TPC;
    // flat iteration -> global k offset (row of samp / column of Wp)
    auto kbase = [&](int it) { return (t0 + (it >> 3)) * 512 + (it & 7) * 64; };

    f32x4 acc[4];
#pragma unroll
    for (int m = 0; m < 4; m++) acc[m] = (f32x4){0.f, 0.f, 0.f, 0.f};

    // prologue: prefetch iteration 0
    uint4 b0, b1;
    bf16x8 areg[8];
    {
        int kb = kbase(0);
        const uint4* g = reinterpret_cast<const uint4*>(&sb[(size_t)(kb + jrow) * 1024 + p0 + pq]);
        b0 = g[0]; b1 = g[1];
#pragma unroll
        for (int ks = 0; ks < 2; ks++)
#pragma unroll
            for (int m = 0; m < 4; m++)
                areg[ks * 4 + m] = *reinterpret_cast<const bf16x8*>(
                    &Wp[(size_t)(arow + m * 16) * KK + kb + ks * 32 + frag_k0]);
    }

    for (int it = 0; it < NIT; ++it) {
        int itn = (it + 1 < NIT) ? it + 1 : it;   // clamp (re-loads last tile, harmless)
        int kbn = kbase(itn);
        // ---- write current B regs to LDS (8 dword stores, row-spread) ----
        {
            unsigned* sd = reinterpret_cast<unsigned*>(&S16[jrow][pq]);
            sd[0] = b0.x; sd[1] = b0.y; sd[2] = b0.z; sd[3] = b0.w;
            sd[4] = b1.x; sd[5] = b1.y; sd[6] = b1.z; sd[7] = b1.w;
        }
        // issue next B loads (overlap with barrier+MFMA phase)
        const uint4* gn = reinterpret_cast<const uint4*>(&sb[(size_t)(kbn + jrow) * 1024 + p0 + pq]);
        uint4 nb0 = gn[0], nb1 = gn[1];
        __syncthreads();
        // ---- MFMA phase using prefetched A ----
#pragma unroll
        for (int ks = 0; ks < 2; ks++) {
            bf16x8 bfrag;
#pragma unroll
            for (int r = 0; r < 8; r++) bfrag[r] = S16[ks * 32 + frag_k0 + r][frag_pix];
#pragma unroll
            for (int m = 0; m < 4; m++)
                acc[m] = __builtin_amdgcn_mfma_f32_16x16x32_bf16(areg[ks * 4 + m], bfrag, acc[m], 0, 0, 0);
        }
        // issue next A loads (overlap with barrier + next LDS-write)
#pragma unroll
        for (int ks = 0; ks < 2; ks++)
#pragma unroll
            for (int m = 0; m < 4; m++)
                areg[ks * 4 + m] = *reinterpret_cast<const bf16x8*>(
                    &Wp[(size_t)(arow + m * 16) * KK + kbn + ks * 32 + frag_k0]);
        b0 = nb0; b1 = nb1;
        __syncthreads();
    }
    int orow = (lane >> 4) * 4;
#pragma unroll
    for (int m = 0; m < 4; m++)
#pragma unroll
        for (int r = 0; r < 4; r++) {
            int oc = oc0 + m * 16 + orow + r;
            atomicAdd(&out[((size_t)b * OCS + ch_off + oc) * 1024 + p0 + frag_pix], acc[m][r]);
        }
}

extern "C" void kernel_launch(void* const* d_in, const int* in_sizes, int n_in,
                              void* d_out, int out_size, void* d_ws, size_t ws_size,
                              hipStream_t stream) {
    const float* x        = (const float*)d_in[0];
    const float* ln1_g    = (const float*)d_in[1];
    const float* ln1_b    = (const float*)d_in[2];
    const float* qkv_w    = (const float*)d_in[3];
    const float* qkv_b    = (const float*)d_in[4];
    const float* merge_w  = (const float*)d_in[5];
    const float* merge_b  = (const float*)d_in[6];
    const float* ibpp_in_w  = (const float*)d_in[7];
    const float* ibpp_in_b  = (const float*)d_in[8];
    const float* ibpp_out_w = (const float*)d_in[9];
    const float* ibpp_out_b = (const float*)d_in[10];
    const float* proj_w   = (const float*)d_in[11];
    const float* proj_b   = (const float*)d_in[12];
    const float* ln2_g    = (const float*)d_in[13];
    const float* ln2_b    = (const float*)d_in[14];
    const float* fc1_w    = (const float*)d_in[15];
    const float* fc1_b    = (const float*)d_in[16];
    const float* dc3_off_w = (const float*)d_in[17];
    const float* dc3_off_b = (const float*)d_in[18];
    const float* dc3_w    = (const float*)d_in[19];
    const float* dc3_b    = (const float*)d_in[20];
    const float* dc5_off_w = (const float*)d_in[21];
    const float* dc5_off_b = (const float*)d_in[22];
    const float* dc5_w    = (const float*)d_in[23];
    const float* dc5_b    = (const float*)d_in[24];
    const float* ffn_g    = (const float*)d_in[25];
    const float* ffn_b    = (const float*)d_in[26];
    const float* fc2_w    = (const float*)d_in[27];
    const float* fc2_b    = (const float*)d_in[28];
    float* outp = (float*)d_out;

    float* ws = (float*)d_ws;
    float* h_buf   = ws;                       // 2048x256
    float* qkv_buf = h_buf + 524288;           // 2048x768
    float* attn_o  = qkv_buf + 1572864;        // 2048x256
    float* cat     = attn_o + 524288;          // 2048x512
    float* xres    = cat + 1048576;            // 2048x256
    float* h2a     = xres + 524288;            // 2048x256
    float* plane   = h2a + 524288;             // 2 x 1024ch x 1024pix
    float* dcv3    = plane + 2097152;          // 2 x 512 x 1024
    float* dcv5    = dcv3 + 1048576;           // 2 x 512 x 1024
    float* hcat    = dcv5 + 1048576;           // 2048 x 1024
    float* hg      = hcat + 2097152;           // 2048 x 1024
    float* off3    = hg + 2097152;             // 2 x 18 x 1024
    float* off5    = off3 + 36864;             // 2 x 50 x 1024
    float* tab3W_f = off5 + 102400;            // 2*9*1024 float4
    float* tab5W_f = tab3W_f + 73728;          // 2*25*1024 float4
    float* tab3O_f = tab5W_f + 204800;         // 2*9*1024 int4
    float* tab5O_f = tab3O_f + 73728;          // 2*25*1024 int4
    short* wp3     = (short*)(tab5O_f + 204800);  // 512x4608 bf16
    short* wp5     = wp3 + 2359296;               // 512x12800 bf16
    short* samp    = wp5 + 6553600;               // 2x25x512x1024 bf16 (shared by all 4 convs)
    float* pcv     = (float*)(samp + 26214400);   // 2 x 1024 x 1024 (plain-conv out, ch-major)

    // ---- prep: W -> bf16 tap-major ----
    wconv_prep_kernel<<<dim3(512, 2), 256, 0, stream>>>(dc3_w, dc5_w, wp3, wp5);

    // ---- attention branch ----
    ln256_kernel<<<2048, 256, 0, stream>>>(x, ln1_g, ln1_b, h_buf);
    gemm64_kernel<<<dim3(12, 32), 256, 0, stream>>>(h_buf, qkv_w, qkv_b, nullptr, qkv_buf,
                                                    256, 256, 768, 768, 0, 0, 0);
    attn_kernel<<<dim3(128, 8, 2), 256, 0, stream>>>(qkv_buf, attn_o);
    gemm64_kernel<<<dim3(4, 32), 256, 0, stream>>>(attn_o, merge_w, merge_b, nullptr, cat,
                                                   256, 256, 256, 512, 0, 0, 0);
    ibpp_kernel<<<256, 256, 0, stream>>>(h_buf, ibpp_in_w, ibpp_in_b, ibpp_out_w, ibpp_out_b, cat);
    gemm64_kernel<<<dim3(4, 32), 256, 0, stream>>>(cat, proj_w, proj_b, x, xres,
                                                   512, 512, 256, 256, 0, 256, 0);
    // ---- EHFF branch ----
    ln256_kernel<<<2048, 256, 0, stream>>>(xres, ln2_g, ln2_b, h2a);
    gemm64_kernel<<<dim3(16, 32), 256, 0, stream>>>(h2a, fc1_w, fc1_b, nullptr, plane,
                                                    256, 256, 1024, 0, 0, 0, 1);
    // offset convs + tables
    hipMemsetAsync(off3, 0, (36864 + 102400) * sizeof(float), stream);
    offconv_kernel<3, 1><<<dim3(4, 18, 32), 256, 0, stream>>>(plane, 0, dc3_off_w, off3, 18);
    offconv_kernel<5, 2><<<dim3(4, 50, 32), 256, 0, stream>>>(plane, 512, dc5_off_w, off5, 50);
    mktab_kernel<3, 1><<<dim3(4, 9, 2), 256, 0, stream>>>(off3, dc3_off_b, (int4*)tab3O_f, (float4*)tab3W_f);
    mktab_kernel<5, 2><<<dim3(4, 25, 2), 256, 0, stream>>>(off5, dc5_off_b, (int4*)tab5O_f, (float4*)tab5W_f);
    initc_kernel<<<1024, 256, 0, stream>>>(dcv3, dc3_b);
    initc_kernel<<<1024, 256, 0, stream>>>(dcv5, dc5_b);
    initpcv_kernel<<<2048, 256, 0, stream>>>(pcv, dc3_b, dc5_b);
    // 3x3: deform sample -> GEMM -> dcv3; plain sample(dcv3) -> GEMM -> pcv[:512]
    dsamp_kernel<9><<<dim3(512, 2), 256, 0, stream>>>(plane, 0,
        (const int4*)tab3O_f, (const float4*)tab3W_f, samp);
    conv_gemm_kernel<9, 3><<<dim3(16, 8, 6), 256, 0, stream>>>(samp, wp3, dcv3, 512, 0);
    psamp_kernel<9><<<dim3(512, 2), 256, 0, stream>>>(dcv3, samp);
    conv_gemm_kernel<9, 3><<<dim3(16, 8, 6), 256, 0, stream>>>(samp, wp3, pcv, 1024, 0);
    // 5x5: deform sample -> GEMM -> dcv5; plain sample(dcv5) -> GEMM -> pcv[512:]
    dsamp_kernel<25><<<dim3(512, 2), 256, 0, stream>>>(plane, 512,
        (const int4*)tab5O_f, (const float4*)tab5W_f, samp);
    conv_gemm_kernel<25, 5><<<dim3(16, 8, 10), 256, 0, stream>>>(samp, wp5, dcv5, 512, 0);
    psamp_kernel<25><<<dim3(512, 2), 256, 0, stream>>>(dcv5, samp);
    conv_gemm_kernel<25, 5><<<dim3(16, 8, 10), 256, 0, stream>>>(samp, wp5, pcv, 1024, 512);
    // transpose plain-conv output into token-major hcat, then LN+GELU and fc2
    tpose_kernel<<<dim3(32, 32, 2), 256, 0, stream>>>(pcv, hcat);
    lngelu_kernel<<<2048, 256, 0, stream>>>(hcat, ffn_g, ffn_b, hg);
    gemm64_kernel<<<dim3(4, 32), 256, 0, stream>>>(hg, fc2_w, fc2_b, xres, outp,
                                                   1024, 1024, 256, 256, 0, 256, 0);
}

// Round 13
// 1387.579 us; speedup vs baseline: 1.4794x; 1.0795x over previous
//
#include <hip/hip_runtime.h>
#include <math.h>

// Shapes: B=2, N=1024 (H=W=32), C=256, HEADS=8, dh=32, HID=1024, H2=512.
#define TOKS 2048

using bf16x8 = __attribute__((ext_vector_type(8))) short;
using f32x4  = __attribute__((ext_vector_type(4))) float;

__device__ __forceinline__ short f2bf(float f) {
    union { float f; unsigned u; } v; v.f = f;
    unsigned r = v.u + 0x7fff + ((v.u >> 16) & 1);   // RNE bf16 (finite inputs)
    return (short)(r >> 16);
}

__device__ __forceinline__ float gelu_exact(float t) {
    return 0.5f * t * (1.f + erff(t * 0.70710678118654752f));
}

// ---------------- LayerNorm over 256 channels ----------------
__global__ __launch_bounds__(256) void ln256_kernel(const float* __restrict__ x,
    const float* __restrict__ g, const float* __restrict__ bb, float* __restrict__ out) {
    __shared__ float r1[4], r2[4], ms[2];
    int row = blockIdx.x, tid = threadIdx.x;
    float v = x[(size_t)row * 256 + tid];
    float s1 = v, s2 = v * v;
#pragma unroll
    for (int o = 32; o; o >>= 1) { s1 += __shfl_down(s1, o); s2 += __shfl_down(s2, o); }
    if ((tid & 63) == 0) { r1[tid >> 6] = s1; r2[tid >> 6] = s2; }
    __syncthreads();
    if (tid == 0) {
        float a = r1[0] + r1[1] + r1[2] + r1[3];
        float c = r2[0] + r2[1] + r2[2] + r2[3];
        float m = a * (1.f / 256.f);
        float var = c * (1.f / 256.f) - m * m;
        ms[0] = m; ms[1] = rsqrtf(var + 1e-5f);
    }
    __syncthreads();
    out[(size_t)row * 256 + tid] = (v - ms[0]) * ms[1] * g[tid] + bb[tid];
}

// ---------------- LayerNorm(1024) + exact GELU ----------------
__global__ __launch_bounds__(256) void lngelu_kernel(const float* __restrict__ hcat,
    const float* __restrict__ g, const float* __restrict__ bb, float* __restrict__ hg) {
    __shared__ float r1[4], r2[4], ms[2];
    int row = blockIdx.x, tid = threadIdx.x;
    float4 v = reinterpret_cast<const float4*>(hcat + (size_t)row * 1024)[tid];
    float s1 = v.x + v.y + v.z + v.w;
    float s2 = v.x * v.x + v.y * v.y + v.z * v.z + v.w * v.w;
#pragma unroll
    for (int o = 32; o; o >>= 1) { s1 += __shfl_down(s1, o); s2 += __shfl_down(s2, o); }
    if ((tid & 63) == 0) { r1[tid >> 6] = s1; r2[tid >> 6] = s2; }
    __syncthreads();
    if (tid == 0) {
        float a = r1[0] + r1[1] + r1[2] + r1[3];
        float c = r2[0] + r2[1] + r2[2] + r2[3];
        float m = a * (1.f / 1024.f);
        float var = c * (1.f / 1024.f) - m * m;
        ms[0] = m; ms[1] = rsqrtf(var + 1e-5f);
    }
    __syncthreads();
    float4 gv = reinterpret_cast<const float4*>(g)[tid];
    float4 bv = reinterpret_cast<const float4*>(bb)[tid];
    float m = ms[0], inv = ms[1];
    float4 o4;
    o4.x = gelu_exact((v.x - m) * inv * gv.x + bv.x);
    o4.y = gelu_exact((v.y - m) * inv * gv.y + bv.y);
    o4.z = gelu_exact((v.z - m) * inv * gv.z + bv.z);
    o4.w = gelu_exact((v.w - m) * inv * gv.w + bv.w);
    reinterpret_cast<float4*>(hg + (size_t)row * 1024)[tid] = o4;
}

// ---------------- generic fp32 tiled GEMM ----------------
__global__ __launch_bounds__(256) void gemm64_kernel(
    const float* __restrict__ A, const float* __restrict__ W,
    const float* __restrict__ bias, const float* __restrict__ resid,
    float* __restrict__ Cout, int K, int lda, int ldw, int ldc,
    int col_off, int ldres, int mode) {
    __shared__ float As[16][64];
    __shared__ float Ws[16][64];
    int tid = threadIdx.x;
    int n0 = blockIdx.x * 64, m0 = blockIdx.y * 64;
    int ty = tid >> 4, tx = tid & 15;
    int amm = tid >> 2, akk = (tid & 3) * 4;
    int wkk = tid >> 4, wnn = (tid & 15) * 4;
    float acc[4][4] = {};
    for (int k0 = 0; k0 < K; k0 += 16) {
        float4 a4 = *reinterpret_cast<const float4*>(&A[(size_t)(m0 + amm) * lda + k0 + akk]);
        float4 w4 = *reinterpret_cast<const float4*>(&W[(size_t)(k0 + wkk) * ldw + n0 + wnn]);
        As[akk + 0][amm] = a4.x; As[akk + 1][amm] = a4.y;
        As[akk + 2][amm] = a4.z; As[akk + 3][amm] = a4.w;
        *reinterpret_cast<float4*>(&Ws[wkk][wnn]) = w4;
        __syncthreads();
#pragma unroll
        for (int kk = 0; kk < 16; kk++) {
            float4 av = *reinterpret_cast<const float4*>(&As[kk][ty * 4]);
            float4 bv = *reinterpret_cast<const float4*>(&Ws[kk][tx * 4]);
            float a[4] = {av.x, av.y, av.z, av.w};
            float b[4] = {bv.x, bv.y, bv.z, bv.w};
#pragma unroll
            for (int i = 0; i < 4; i++)
#pragma unroll
                for (int j = 0; j < 4; j++) acc[i][j] += a[i] * b[j];
        }
        __syncthreads();
    }
#pragma unroll
    for (int i = 0; i < 4; i++) {
        int r = m0 + ty * 4 + i;
#pragma unroll
        for (int j = 0; j < 4; j++) {
            int c = n0 + tx * 4 + j;
            float v = acc[i][j] + bias[c];
            if (resid) v += resid[(size_t)r * ldres + c];
            if (mode == 0) Cout[(size_t)r * ldc + col_off + c] = v;
            else Cout[(size_t)(r >> 10) * 1048576 + (size_t)c * 1024 + (r & 1023)] = v;
        }
    }
}

// ---------------- attention: one block per (b, head, 8 q-rows) ----------------
#define QT 8
__global__ __launch_bounds__(256) void attn_kernel(const float* __restrict__ qkv,
                                                   float* __restrict__ attn_o) {
    __shared__ float S[QT][1028];
    __shared__ float KV[128][33];
    __shared__ float rowsum[QT];
    int tid = threadIdx.x;
    int qt = blockIdx.x, hd = blockIdx.y, b = blockIdx.z;
    const float* base = qkv + (size_t)b * 1024 * 768;
    int q0 = qt * QT;
    int sqi = tid >> 5, sks = tid & 31;
    float qreg[32];
    const float* qp = base + (size_t)(q0 + sqi) * 768 + hd * 32;
#pragma unroll
    for (int d = 0; d < 32; d++) qreg[d] = qp[d];
    for (int kc = 0; kc < 1024; kc += 128) {
        __syncthreads();
        for (int i = tid; i < 128 * 32; i += 256) {
            int ki = i >> 5, d = i & 31;
            KV[ki][d] = base[(size_t)(kc + ki) * 768 + 256 + hd * 32 + d];
        }
        __syncthreads();
#pragma unroll
        for (int s = 0; s < 4; s++) {
            int ki = sks + 32 * s;
            float acc = 0.f;
#pragma unroll
            for (int d = 0; d < 32; d++) acc += qreg[d] * KV[ki][d];
            S[sqi][kc + ki] = acc * 0.17677669529663687f;
        }
    }
    __syncthreads();
    {
        int row = tid >> 5, l = tid & 31;
        float mx = -1e30f;
        for (int i = l; i < 1024; i += 32) mx = fmaxf(mx, S[row][i]);
#pragma unroll
        for (int o = 16; o; o >>= 1) mx = fmaxf(mx, __shfl_xor(mx, o));
        float sum = 0.f;
        for (int i = l; i < 1024; i += 32) {
            float e = __expf(S[row][i] - mx);
            S[row][i] = e; sum += e;
        }
#pragma unroll
        for (int o = 16; o; o >>= 1) sum += __shfl_xor(sum, o);
        if (l == 0) rowsum[row] = sum;
    }
    float acc = 0.f;
    int d = tid & 31, qi = tid >> 5;
    for (int vc = 0; vc < 1024; vc += 128) {
        __syncthreads();
        for (int i = tid; i < 128 * 32; i += 256) {
            int ki = i >> 5, dd = i & 31;
            KV[ki][dd] = base[(size_t)(vc + ki) * 768 + 512 + hd * 32 + dd];
        }
        __syncthreads();
        for (int m = 0; m < 128; m++) acc += S[qi][vc + m] * KV[m][d];
    }
    attn_o[(size_t)((b << 10) + q0 + qi) * 256 + hd * 32 + d] = acc / rowsum[qi];
}

// ---------------- ibpp grouped 8x8 linears ----------------
__global__ __launch_bounds__(256) void ibpp_kernel(
    const float* __restrict__ h, const float* __restrict__ wi, const float* __restrict__ bi,
    const float* __restrict__ wo, const float* __restrict__ bo, float* __restrict__ cat) {
    __shared__ float Wi[64], Wo[64], Bi[8], Bo[8];
    int tid = threadIdx.x;
    if (tid < 64) { Wi[tid] = wi[tid]; Wo[tid] = wo[tid]; }
    if (tid < 8) { Bi[tid] = bi[tid]; Bo[tid] = bo[tid]; }
    __syncthreads();
    int gi = blockIdx.x * 256 + tid;
    int tok = gi >> 5, grp = gi & 31;
    const float* hp = h + (size_t)tok * 256 + grp * 8;
    float4 a = *reinterpret_cast<const float4*>(hp);
    float4 b4 = *reinterpret_cast<const float4*>(hp + 4);
    float v[8] = {a.x, a.y, a.z, a.w, b4.x, b4.y, b4.z, b4.w};
    float tm[8];
#pragma unroll
    for (int j = 0; j < 8; j++) {
        float s = Bi[j];
#pragma unroll
        for (int i = 0; i < 8; i++) s += v[i] * Wi[i * 8 + j];
        tm[j] = s / (1.f + __expf(-s));
    }
    float* cp = cat + (size_t)tok * 512 + 256 + grp * 8;
#pragma unroll
    for (int j = 0; j < 8; j++) {
        float s = Bo[j];
#pragma unroll
        for (int i = 0; i < 8; i++) s += tm[i] * Wo[i * 8 + j];
        cp[j] = s;
    }
}

// ---------------- offset conv v4: X-reuse across all OC, 64 chunks of 8 ch ----------------
// grid (4 pixblk, b*64 + cc). All OC accumulated in registers; W reads wave-uniform.
template <int K, int PAD, int OC>
__global__ __launch_bounds__(256) void offconv_kernel(
    const float* __restrict__ plane, int coff,
    const float* __restrict__ W, float* __restrict__ out) {
    const int K2 = K * K;
    int pix = blockIdx.x * 256 + threadIdx.x;
    int zb = blockIdx.y;
    int b = zb >> 6, cc = zb & 63;          // 64 chunks of 8 channels
    int h = pix >> 5, w = pix & 31;
    int vofs[K2]; float vmsk[K2];
#pragma unroll
    for (int t = 0; t < K2; t++) {
        int yy = h + t / K - PAD, xx = w + t % K - PAD;
        bool v = (yy >= 0 && yy < 32 && xx >= 0 && xx < 32);
        int yc = min(max(yy, 0), 31), xc = min(max(xx, 0), 31);
        vofs[t] = yc * 32 + xc; vmsk[t] = v ? 1.f : 0.f;
    }
    const float* Xb = plane + (size_t)b * 1048576 + (size_t)(coff + cc * 8) * 1024;
    const float* Wb = W + (size_t)(cc * 8) * K2;       // + oc*512*K2 + c*K2 + t
    float acc[OC] = {};
    for (int c = 0; c < 8; c++) {
        const float* Xc = Xb + (size_t)c * 1024;
        float xs[K2];
#pragma unroll
        for (int t = 0; t < K2; t++) xs[t] = Xc[vofs[t]] * vmsk[t];
        const float* Wc = Wb + c * K2;
#pragma unroll
        for (int oc = 0; oc < OC; oc++)
#pragma unroll
            for (int t = 0; t < K2; t++)
                acc[oc] += Wc[(size_t)oc * 512 * K2 + t] * xs[t];
    }
#pragma unroll
    for (int oc = 0; oc < OC; oc++)
        atomicAdd(&out[((size_t)b * OC + oc) * 1024 + pix], acc[oc]);
}

// ---------------- bilinear table build (adds offset bias) ----------------
template <int K, int PAD>
__global__ __launch_bounds__(256) void mktab_kernel(
    const float* __restrict__ off, const float* __restrict__ off_b,
    int4* __restrict__ tabO, float4* __restrict__ tabW) {
    const int K2 = K * K;
    int pix = blockIdx.x * 256 + threadIdx.x;
    int t = blockIdx.y, b = blockIdx.z;
    int h = pix >> 5, w = pix & 31;
    float oy = off[((size_t)(b * 2 * K2) + 2 * t) * 1024 + pix] + off_b[2 * t];
    float ox = off[((size_t)(b * 2 * K2) + 2 * t + 1) * 1024 + pix] + off_b[2 * t + 1];
    float py = (float)(h - PAD + t / K) + oy;
    float px = (float)(w - PAD + t % K) + ox;
    float y0f = floorf(py), x0f = floorf(px);
    float dy = py - y0f, dx = px - x0f;
    int y0 = (int)y0f, x0 = (int)x0f;
    int4 o; float4 wt;
    auto mk = [&](int iy, int ix, float wgt, int& oo, float& ww) {
        bool v = (iy >= 0 && iy <= 31 && ix >= 0 && ix <= 31);
        int iyc = min(max(iy, 0), 31), ixc = min(max(ix, 0), 31);
        oo = iyc * 32 + ixc; ww = v ? wgt : 0.f;
    };
    mk(y0, x0, (1.f - dy) * (1.f - dx), o.x, wt.x);
    mk(y0, x0 + 1, (1.f - dy) * dx, o.y, wt.y);
    mk(y0 + 1, x0, dy * (1.f - dx), o.z, wt.z);
    mk(y0 + 1, x0 + 1, dy * dx, o.w, wt.w);
    tabO[((size_t)b * K2 + t) * 1024 + pix] = o;
    tabW[((size_t)b * K2 + t) * 1024 + pix] = wt;
}

// ---------------- W prep: fp32 OIHW -> bf16 tap-major Wp[oc][t*512+c] ----------------
__global__ __launch_bounds__(256) void wconv_prep_kernel(
    const float* __restrict__ w3, const float* __restrict__ w5,
    short* __restrict__ wp3, short* __restrict__ wp5) {
    __shared__ float wl[12800];
    int oc = blockIdx.x, sel = blockIdx.y, tid = threadIdx.x;
    const int K2 = sel ? 25 : 9;
    const int KK = K2 * 512;
    const float* src = (sel ? w5 : w3) + (size_t)oc * KK;
    short* dst = (sel ? wp5 : wp3) + (size_t)oc * KK;
    for (int i = tid; i < KK; i += 256) wl[i] = src[i];
    __syncthreads();
    for (int i = tid; i < KK; i += 256) {
        int t = i >> 9, c = i & 511;
        dst[i] = f2bf(wl[c * K2 + t]);
    }
}

// ---------------- output init with bias ----------------
__global__ __launch_bounds__(256) void initc_kernel(float* __restrict__ dst,
                                                    const float* __restrict__ bias) {
    int row = blockIdx.x;             // b*512 + oc, grid 1024
    float v = bias[row & 511];
    reinterpret_cast<float4*>(dst + (size_t)row * 1024)[threadIdx.x] = make_float4(v, v, v, v);
}

__global__ __launch_bounds__(256) void initpcv_kernel(float* __restrict__ pcv,
    const float* __restrict__ b3, const float* __restrict__ b5) {
    int row = blockIdx.x;             // b*1024 + ch, grid 2048
    int ch = row & 1023;
    float v = ch < 512 ? b3[ch] : b5[ch - 512];
    reinterpret_cast<float4*>(pcv + (size_t)row * 1024)[threadIdx.x] = make_float4(v, v, v, v);
}

// transpose pcv[b][ch][pix] -> hcat[b*1024+pix][ch]
__global__ __launch_bounds__(256) void tpose_kernel(const float* __restrict__ pcv,
                                                    float* __restrict__ hcat) {
    __shared__ float T[32][33];
    int px0 = blockIdx.x * 32, ch0 = blockIdx.y * 32, b = blockIdx.z;
    int tx = threadIdx.x & 31, ty = threadIdx.x >> 5;   // 32x8
    const float* src = pcv + ((size_t)b * 1024 + ch0) * 1024 + px0;
#pragma unroll
    for (int i = 0; i < 4; i++) {
        int r = ty + i * 8;
        T[r][tx] = src[(size_t)r * 1024 + tx];
    }
    __syncthreads();
    float* dst = hcat + ((size_t)(b << 10) + px0) * 1024 + ch0;
#pragma unroll
    for (int i = 0; i < 4; i++) {
        int r = ty + i * 8;
        dst[(size_t)r * 1024 + tx] = T[tx][r];
    }
}

// ---------------- deform sampling: LDS-staged channel, LDS gather -> bf16 samp ----------------
template <int K2>
__global__ __launch_bounds__(256) void dsamp_kernel(
    const float* __restrict__ plane, int coff,
    const int4* __restrict__ tabO, const float4* __restrict__ tabW,
    short* __restrict__ samp) {
    __shared__ float Xl[1024];
    int c = blockIdx.x, b = blockIdx.y, tid = threadIdx.x;
    const float* Xc = plane + (size_t)b * 1048576 + (size_t)(coff + c) * 1024;
    reinterpret_cast<float4*>(Xl)[tid] = reinterpret_cast<const float4*>(Xc)[tid];
    __syncthreads();
    const int4* tO = tabO + (size_t)b * K2 * 1024;
    const float4* tW = tabW + (size_t)b * K2 * 1024;
    short* sb = samp + (size_t)b * K2 * 512 * 1024;
    int p4 = tid * 4;
    for (int t = 0; t < K2; t++) {
        short4 r4;
        short* rp = (short*)&r4;
#pragma unroll
        for (int q = 0; q < 4; q++) {
            int4 o = tO[t * 1024 + p4 + q];
            float4 wv = tW[t * 1024 + p4 + q];
            float v = wv.x * Xl[o.x] + wv.y * Xl[o.y] + wv.z * Xl[o.z] + wv.w * Xl[o.w];
            rp[q] = f2bf(v);
        }
        *reinterpret_cast<short4*>(&sb[(size_t)(t * 512 + c) * 1024 + p4]) = r4;
    }
}

// ---------------- plain-conv sampling: constant shifts from dcv -> bf16 samp ----------------
template <int K2>
__global__ __launch_bounds__(256) void psamp_kernel(
    const float* __restrict__ dcv, short* __restrict__ samp) {
    const int K = (K2 == 9) ? 3 : 5, PAD = (K2 == 9) ? 1 : 2;
    __shared__ float Xl[1024];
    int c = blockIdx.x, b = blockIdx.y, tid = threadIdx.x;
    const float* Xc = dcv + ((size_t)b * 512 + c) * 1024;
    reinterpret_cast<float4*>(Xl)[tid] = reinterpret_cast<const float4*>(Xc)[tid];
    __syncthreads();
    short* sb = samp + (size_t)b * K2 * 512 * 1024;
    int p4 = tid * 4;
    int h = p4 >> 5, w0 = p4 & 31;     // 4 consecutive pixels, same image row
    for (int t = 0; t < K2; t++) {
        int dy = t / K - PAD, dx = t % K - PAD;
        int yy = h + dy;
        bool vy = ((unsigned)yy < 32u);
        int yb = (vy ? yy : 0) << 5;
        short4 r4;
        short* rp = (short*)&r4;
#pragma unroll
        for (int q = 0; q < 4; q++) {
            int xx = w0 + q + dx;
            bool v = vy && ((unsigned)xx < 32u);
            rp[q] = f2bf(v ? Xl[yb + xx] : 0.f);
        }
        *reinterpret_cast<short4*>(&sb[(size_t)(t * 512 + c) * 1024 + p4]) = r4;
    }
}

// ======== unified conv GEMM: bf16 MFMA, register-prefetch pipeline ========
// Tile 64 oc x 64 pix, 4 waves; K-chunk = TPC taps; atomics into bias-init'd out.
template <int K2, int TPC>
__global__ __launch_bounds__(256, 4) void conv_gemm_kernel(
    const short* __restrict__ samp, const short* __restrict__ Wp,
    float* __restrict__ out, int OCS, int ch_off) {
    __shared__ short S16[64][66];            // 132-B rows: dword offset 33/row -> bank spread
    const int KK = 512 * K2;
    const int NCHUNK = K2 / TPC;
    const int NIT = TPC * 8;                 // c0 steps of 64 over the chunk
    int tid = threadIdx.x;
    int lane = tid & 63, wave = tid >> 6;
    int p0 = blockIdx.x * 64, oc0 = blockIdx.y * 64;
    int bz = blockIdx.z;
    int b = bz / NCHUNK, chunk = bz % NCHUNK;
    int jrow = tid >> 2, pq = (tid & 3) * 16;   // staging: 64 rows x 64 pix, 32 B/thread
    int frag_pix = wave * 16 + (lane & 15);
    int frag_k0 = (lane >> 4) * 8;
    int arow = oc0 + (lane & 15);
    const short* sb = samp + (size_t)b * KK * 1024;
    int t0 = chunk * TPC;
    auto kbase = [&](int it) { return (t0 + (it >> 3)) * 512 + (it & 7) * 64; };

    f32x4 acc[4];
#pragma unroll
    for (int m = 0; m < 4; m++) acc[m] = (f32x4){0.f, 0.f, 0.f, 0.f};

    uint4 b0, b1;
    bf16x8 areg[8];
    {
        int kb = kbase(0);
        const uint4* g = reinterpret_cast<const uint4*>(&sb[(size_t)(kb + jrow) * 1024 + p0 + pq]);
        b0 = g[0]; b1 = g[1];
#pragma unroll
        for (int ks = 0; ks < 2; ks++)
#pragma unroll
            for (int m = 0; m < 4; m++)
                areg[ks * 4 + m] = *reinterpret_cast<const bf16x8*>(
                    &Wp[(size_t)(arow + m * 16) * KK + kb + ks * 32 + frag_k0]);
    }

    for (int it = 0; it < NIT; ++it) {
        int itn = (it + 1 < NIT) ? it + 1 : it;
        int kbn = kbase(itn);
        {
            unsigned* sd = reinterpret_cast<unsigned*>(&S16[jrow][pq]);
            sd[0] = b0.x; sd[1] = b0.y; sd[2] = b0.z; sd[3] = b0.w;
            sd[4] = b1.x; sd[5] = b1.y; sd[6] = b1.z; sd[7] = b1.w;
        }
        const uint4* gn = reinterpret_cast<const uint4*>(&sb[(size_t)(kbn + jrow) * 1024 + p0 + pq]);
        uint4 nb0 = gn[0], nb1 = gn[1];
        __syncthreads();
#pragma unroll
        for (int ks = 0; ks < 2; ks++) {
            bf16x8 bfrag;
#pragma unroll
            for (int r = 0; r < 8; r++) bfrag[r] = S16[ks * 32 + frag_k0 + r][frag_pix];
#pragma unroll
            for (int m = 0; m < 4; m++)
                acc[m] = __builtin_amdgcn_mfma_f32_16x16x32_bf16(areg[ks * 4 + m], bfrag, acc[m], 0, 0, 0);
        }
#pragma unroll
        for (int ks = 0; ks < 2; ks++)
#pragma unroll
            for (int m = 0; m < 4; m++)
                areg[ks * 4 + m] = *reinterpret_cast<const bf16x8*>(
                    &Wp[(size_t)(arow + m * 16) * KK + kbn + ks * 32 + frag_k0]);
        b0 = nb0; b1 = nb1;
        __syncthreads();
    }
    int orow = (lane >> 4) * 4;
#pragma unroll
    for (int m = 0; m < 4; m++)
#pragma unroll
        for (int r = 0; r < 4; r++) {
            int oc = oc0 + m * 16 + orow + r;
            atomicAdd(&out[((size_t)b * OCS + ch_off + oc) * 1024 + p0 + frag_pix], acc[m][r]);
        }
}

extern "C" void kernel_launch(void* const* d_in, const int* in_sizes, int n_in,
                              void* d_out, int out_size, void* d_ws, size_t ws_size,
                              hipStream_t stream) {
    const float* x        = (const float*)d_in[0];
    const float* ln1_g    = (const float*)d_in[1];
    const float* ln1_b    = (const float*)d_in[2];
    const float* qkv_w    = (const float*)d_in[3];
    const float* qkv_b    = (const float*)d_in[4];
    const float* merge_w  = (const float*)d_in[5];
    const float* merge_b  = (const float*)d_in[6];
    const float* ibpp_in_w  = (const float*)d_in[7];
    const float* ibpp_in_b  = (const float*)d_in[8];
    const float* ibpp_out_w = (const float*)d_in[9];
    const float* ibpp_out_b = (const float*)d_in[10];
    const float* proj_w   = (const float*)d_in[11];
    const float* proj_b   = (const float*)d_in[12];
    const float* ln2_g    = (const float*)d_in[13];
    const float* ln2_b    = (const float*)d_in[14];
    const float* fc1_w    = (const float*)d_in[15];
    const float* fc1_b    = (const float*)d_in[16];
    const float* dc3_off_w = (const float*)d_in[17];
    const float* dc3_off_b = (const float*)d_in[18];
    const float* dc3_w    = (const float*)d_in[19];
    const float* dc3_b    = (const float*)d_in[20];
    const float* dc5_off_w = (const float*)d_in[21];
    const float* dc5_off_b = (const float*)d_in[22];
    const float* dc5_w    = (const float*)d_in[23];
    const float* dc5_b    = (const float*)d_in[24];
    const float* ffn_g    = (const float*)d_in[25];
    const float* ffn_b    = (const float*)d_in[26];
    const float* fc2_w    = (const float*)d_in[27];
    const float* fc2_b    = (const float*)d_in[28];
    float* outp = (float*)d_out;

    float* ws = (float*)d_ws;
    float* h_buf   = ws;                       // 2048x256
    float* qkv_buf = h_buf + 524288;           // 2048x768
    float* attn_o  = qkv_buf + 1572864;        // 2048x256
    float* cat     = attn_o + 524288;          // 2048x512
    float* xres    = cat + 1048576;            // 2048x256
    float* h2a     = xres + 524288;            // 2048x256
    float* plane   = h2a + 524288;             // 2 x 1024ch x 1024pix
    float* dcv3    = plane + 2097152;          // 2 x 512 x 1024
    float* dcv5    = dcv3 + 1048576;           // 2 x 512 x 1024
    float* hcat    = dcv5 + 1048576;           // 2048 x 1024
    float* hg      = hcat + 2097152;           // 2048 x 1024
    float* off3    = hg + 2097152;             // 2 x 18 x 1024
    float* off5    = off3 + 36864;             // 2 x 50 x 1024
    float* tab3W_f = off5 + 102400;            // 2*9*1024 float4
    float* tab5W_f = tab3W_f + 73728;          // 2*25*1024 float4
    float* tab3O_f = tab5W_f + 204800;         // 2*9*1024 int4
    float* tab5O_f = tab3O_f + 73728;          // 2*25*1024 int4
    short* wp3     = (short*)(tab5O_f + 204800);  // 512x4608 bf16
    short* wp5     = wp3 + 2359296;               // 512x12800 bf16
    short* samp    = wp5 + 6553600;               // 2x25x512x1024 bf16 (shared by all 4 convs)
    float* pcv     = (float*)(samp + 26214400);   // 2 x 1024 x 1024 (plain-conv out, ch-major)

    // ---- prep: W -> bf16 tap-major ----
    wconv_prep_kernel<<<dim3(512, 2), 256, 0, stream>>>(dc3_w, dc5_w, wp3, wp5);

    // ---- attention branch ----
    ln256_kernel<<<2048, 256, 0, stream>>>(x, ln1_g, ln1_b, h_buf);
    gemm64_kernel<<<dim3(12, 32), 256, 0, stream>>>(h_buf, qkv_w, qkv_b, nullptr, qkv_buf,
                                                    256, 256, 768, 768, 0, 0, 0);
    attn_kernel<<<dim3(128, 8, 2), 256, 0, stream>>>(qkv_buf, attn_o);
    gemm64_kernel<<<dim3(4, 32), 256, 0, stream>>>(attn_o, merge_w, merge_b, nullptr, cat,
                                                   256, 256, 256, 512, 0, 0, 0);
    ibpp_kernel<<<256, 256, 0, stream>>>(h_buf, ibpp_in_w, ibpp_in_b, ibpp_out_w, ibpp_out_b, cat);
    gemm64_kernel<<<dim3(4, 32), 256, 0, stream>>>(cat, proj_w, proj_b, x, xres,
                                                   512, 512, 256, 256, 0, 256, 0);
    // ---- EHFF branch ----
    ln256_kernel<<<2048, 256, 0, stream>>>(xres, ln2_g, ln2_b, h2a);
    gemm64_kernel<<<dim3(16, 32), 256, 0, stream>>>(h2a, fc1_w, fc1_b, nullptr, plane,
                                                    256, 256, 1024, 0, 0, 0, 1);
    // offset convs + tables
    hipMemsetAsync(off3, 0, (36864 + 102400) * sizeof(float), stream);
    offconv_kernel<3, 1, 18><<<dim3(4, 128), 256, 0, stream>>>(plane, 0, dc3_off_w, off3);
    offconv_kernel<5, 2, 50><<<dim3(4, 128), 256, 0, stream>>>(plane, 512, dc5_off_w, off5);
    mktab_kernel<3, 1><<<dim3(4, 9, 2), 256, 0, stream>>>(off3, dc3_off_b, (int4*)tab3O_f, (float4*)tab3W_f);
    mktab_kernel<5, 2><<<dim3(4, 25, 2), 256, 0, stream>>>(off5, dc5_off_b, (int4*)tab5O_f, (float4*)tab5W_f);
    initc_kernel<<<1024, 256, 0, stream>>>(dcv3, dc3_b);
    initc_kernel<<<1024, 256, 0, stream>>>(dcv5, dc5_b);
    initpcv_kernel<<<2048, 256, 0, stream>>>(pcv, dc3_b, dc5_b);
    // 3x3: deform sample -> GEMM -> dcv3; plain sample(dcv3) -> GEMM -> pcv[:512]
    dsamp_kernel<9><<<dim3(512, 2), 256, 0, stream>>>(plane, 0,
        (const int4*)tab3O_f, (const float4*)tab3W_f, samp);
    conv_gemm_kernel<9, 3><<<dim3(16, 8, 6), 256, 0, stream>>>(samp, wp3, dcv3, 512, 0);
    psamp_kernel<9><<<dim3(512, 2), 256, 0, stream>>>(dcv3, samp);
    conv_gemm_kernel<9, 3><<<dim3(16, 8, 6), 256, 0, stream>>>(samp, wp3, pcv, 1024, 0);
    // 5x5: deform sample -> GEMM -> dcv5; plain sample(dcv5) -> GEMM -> pcv[512:]
    dsamp_kernel<25><<<dim3(512, 2), 256, 0, stream>>>(plane, 512,
        (const int4*)tab5O_f, (const float4*)tab5W_f, samp);
    conv_gemm_kernel<25, 5><<<dim3(16, 8, 10), 256, 0, stream>>>(samp, wp5, dcv5, 512, 0);
    psamp_kernel<25><<<dim3(512, 2), 256, 0, stream>>>(dcv5, samp);
    conv_gemm_kernel<25, 5><<<dim3(16, 8, 10), 256, 0, stream>>>(samp, wp5, pcv, 1024, 512);
    // transpose plain-conv output into token-major hcat, then LN+GELU and fc2
    tpose_kernel<<<dim3(32, 32, 2), 256, 0, stream>>>(pcv, hcat);
    lngelu_kernel<<<2048, 256, 0, stream>>>(hcat, ffn_g, ffn_b, hg);
    gemm64_kernel<<<dim3(4, 32), 256, 0, stream>>>(hg, fc2_w, fc2_b, xres, outp,
                                                   1024, 1024, 256, 256, 0, 256, 0);
}